// Round 12
// baseline (148.967 us; speedup 1.0000x reference)
//
#include <hip/hip_runtime.h>
#include <hip/hip_bf16.h>
#include <cstdint>
#include <cstddef>

typedef __bf16 bf16;
typedef __attribute__((ext_vector_type(8))) __bf16 bf16x8;
typedef __attribute__((ext_vector_type(4))) __bf16 bf16x4;
typedef __attribute__((ext_vector_type(4))) float f32x4;
typedef __attribute__((ext_vector_type(4))) short s16x4;

#define B_ 2
#define S_ 2048
#define D_ 1024
#define H_ 16
#define DK_ 64
#define NROWS (B_*S_)   // 4096
#define NBIAS 4095      // rel in [-2047,2047]
#define LDQ 3072        // fused QKV row stride
#define LOG2E 1.44269504f

__device__ __forceinline__ void async16(void* lds, const void* g) {
  __builtin_amdgcn_global_load_lds(
      (const __attribute__((address_space(1))) void*)g,
      (__attribute__((address_space(3))) void*)lds, 16, 0, 0);
}

__device__ __forceinline__ f32x4 mfma16(bf16x8 a, bf16x8 b, f32x4 c) {
  return __builtin_amdgcn_mfma_f32_16x16x32_bf16(a, b, c, 0, 0, 0);
}

__device__ __forceinline__ s16x4 bc4(bf16x4 x) {
  union { bf16x4 b; s16x4 s; } u; u.b = x; return u.s;
}

// K=16 MFMA: pairs with the swapped-QK^T C-layout (verified R3-R11).
__device__ __forceinline__ f32x4 mfma16k(bf16x4 a, bf16x4 b, f32x4 c) {
  return __builtin_amdgcn_mfma_f32_16x16x16bf16_1k(bc4(a), bc4(b), c, 0, 0, 0);
}

// Hazard-safe single-instruction HW exp2 (R8 lesson: raw asm corrupts).
__device__ __forceinline__ float exp2_hw(float x) {
  return __builtin_amdgcn_exp2f(x);
}

// -------------------------------------------------------- fused prep kernel
__global__ void prep_kernel(const float* __restrict__ X,
                            const float* __restrict__ Wq, const float* __restrict__ Wk,
                            const float* __restrict__ Wv, const float* __restrict__ Wo,
                            const float* __restrict__ rel_emb,
                            bf16* __restrict__ Xb, bf16* __restrict__ oqkv,
                            bf16* __restrict__ oo, float* __restrict__ tab) {
  const int bid = blockIdx.x;
  const int tid = threadIdx.x;
  if (bid < 4096) {
    int i = bid * 256 + tid;
    float4 v = ((const float4*)X)[i];
    bf16x4 o;
    o[0] = (bf16)v.x; o[1] = (bf16)v.y; o[2] = (bf16)v.z; o[3] = (bf16)v.w;
    ((bf16x4*)Xb)[i] = o;
  } else if (bid < 8192) {
    int widx = bid - 4096;
    int y = widx >> 10;
    const float* src = (y == 0) ? Wq : (y == 1) ? Wk : (y == 2) ? Wv : Wo;
    bf16* dst = (y < 3) ? (oqkv + (size_t)y * D_ * D_) : oo;
    int i = (widx & 1023) * 256 + tid;
    float4 v = ((const float4*)src)[i];
    bf16x4 o;
    o[0] = (bf16)v.x; o[1] = (bf16)v.y; o[2] = (bf16)v.z; o[3] = (bf16)v.w;
    ((bf16x4*)dst)[i] = o;
  } else {
    int idx = (bid - 8192) * 256 + tid;
    if (idx >= H_ * NBIAS) return;
    int h = idx / NBIAS;
    int p = idx - h * NBIAS;
    int rel = p - 2047;          // k - q  (mem - ctx)
    int n = -rel;                // per reference: n = -relative_position
    int ret = 0;
    if (n < 0) { ret = 16; n = -n; }
    int bucket;
    if (n < 8) {
      bucket = ret + n;
    } else {
      double v = log((double)n / 8.0) / log(16.0) * 8.0;
      int vi = 8 + (int)v;
      if (vi > 15) vi = 15;
      bucket = ret + vi;
    }
    tab[idx] = rel_emb[bucket * H_ + h] * LOG2E;
  }
}

// ---------------------------------------------------------------- GEMM (bt)
// C[M][N] = alpha * A[M][K] @ B[N][K]^T ; alpha = (n0 < colThr) ? a0 : a1
// Tile (MF*32) x 128 x BK64; 4 waves (2x2); wave (MF*16) x 64.
// VT_EP: blocks with n0 >= vThr write their tile TRANSPOSED to VT.
template<int OUT_BF16, int MF, int VT_EP>
__global__ __launch_bounds__(256, 3)
void gemm_bt(const bf16* __restrict__ A, const bf16* __restrict__ Bw,
             void* __restrict__ C, bf16* __restrict__ VT, int vThr,
             int M, int N, int K, int colThr, float a0, float a1) {
  __shared__ bf16 smem[MF * 32 * 64 + 128 * 64];
  bf16* As = smem;
  bf16* Bs = smem + MF * 32 * 64;
  const int tid = threadIdx.x;
  const int lane = tid & 63;
  const int w = tid >> 6;
  const int wr = w >> 1, wc = w & 1;
  const int l15 = lane & 15, lhi = lane >> 4;
  const int m0 = blockIdx.y * (MF * 32), n0 = blockIdx.x * 128;
  const float alpha = (n0 < colThr) ? a0 : a1;

  f32x4 acc[MF][4] = {};

  const int urow = tid >> 3;                 // 0..31
  const int uswz = (tid & 7) ^ (urow & 7);   // pre-swizzled global 16B unit
  const bf16* ga = A  + (size_t)(m0 + urow) * K + uswz * 8;
  const bf16* gb = Bw + (size_t)(n0 + urow) * K + uswz * 8;

  for (int kt = 0; kt < K; kt += 64) {
#pragma unroll
    for (int rnd = 0; rnd < MF; ++rnd)
      async16(As + tid * 8 + rnd * 2048, ga + kt + (size_t)(rnd * 32) * K);
#pragma unroll
    for (int rnd = 0; rnd < 4; ++rnd)
      async16(Bs + tid * 8 + rnd * 2048, gb + kt + (size_t)(rnd * 32) * K);
    __syncthreads();

#pragma unroll
    for (int kc = 0; kc < 2; ++kc) {
      bf16x8 af[MF], bfr[4];
#pragma unroll
      for (int m = 0; m < MF; ++m) {
        int row = wr * (MF * 16) + m * 16 + l15;
        int off = (row * 64 + kc * 32 + lhi * 8) ^ ((row & 7) << 3);
        af[m] = *(const bf16x8*)&As[off];
      }
#pragma unroll
      for (int n = 0; n < 4; ++n) {
        int row = wc * 64 + n * 16 + l15;
        int off = (row * 64 + kc * 32 + lhi * 8) ^ ((row & 7) << 3);
        bfr[n] = *(const bf16x8*)&Bs[off];
      }
      __builtin_amdgcn_s_setprio(1);
#pragma unroll
      for (int m = 0; m < MF; ++m)
#pragma unroll
        for (int n = 0; n < 4; ++n)
          acc[m][n] = mfma16(af[m], bfr[n], acc[m][n]);
      __builtin_amdgcn_s_setprio(0);
    }
    __syncthreads();
  }

  if (VT_EP && n0 >= vThr) {
    bf16* T = smem;  // 128*128 bf16 = 32 KB
#pragma unroll
    for (int m = 0; m < MF; ++m)
#pragma unroll
      for (int n = 0; n < 4; ++n)
#pragma unroll
        for (int r = 0; r < 4; ++r) {
          int rl = wr * (MF * 16) + m * 16 + lhi * 4 + r;  // s-local
          int cl = wc * 64 + n * 16 + l15;                 // d-local
          T[cl * 128 + (rl ^ ((cl & 7) << 3))] = (bf16)(acc[m][n][r] * alpha);
        }
    __syncthreads();
    const int bb = m0 >> 11, s0l = m0 & 2047, d0 = n0 - vThr;
    const int dr = tid >> 1, sh = tid & 1;
    bf16* dst = VT + ((size_t)(bb * 1024 + d0 + dr)) * 2048 + s0l + sh * 64;
    const bf16* src = T + dr * 128;
#pragma unroll
    for (int i = 0; i < 8; ++i) {
      int sb = sh * 8 + i;
      *(bf16x8*)(dst + i * 8) = *(const bf16x8*)(src + ((sb ^ (dr & 7)) * 8));
    }
    return;
  }

#pragma unroll
  for (int m = 0; m < MF; ++m)
#pragma unroll
    for (int n = 0; n < 4; ++n)
#pragma unroll
      for (int r = 0; r < 4; ++r) {
        int row = m0 + wr * (MF * 16) + m * 16 + lhi * 4 + r;
        int col = n0 + wc * 64 + n * 16 + l15;
        float v = acc[m][n][r] * alpha;
        if (OUT_BF16) ((bf16*)C)[(size_t)row * N + col] = (bf16)v;
        else          ((float*)C)[(size_t)row * N + col] = v;
      }
}

// ---------------------------------------------------------------- attention
// R12: 512 threads = 8 waves. QBLK=128; waves 0-3 process KV [0,1024),
// waves 4-7 process KV [1024,2048) over the SAME q-rows (wave w&3 owns 32).
// No-max softmax => halves merge by plain addition at the end (LDS merge).
// Keeps R11's halved LDS traffic (tile staged once/block, read by 4 waves)
// while restoring 4 waves/SIMD (2 blocks/CU x 16 waves).  LDS 66KB.
__global__ __launch_bounds__(512, 4)
void attn_fwd(const bf16* __restrict__ QKV, const bf16* __restrict__ VTg_,
              const float* __restrict__ biasTab, const float* __restrict__ rel_emb,
              bf16* __restrict__ Og) {
  // [0..3]: K bufs (half*2+dbuf) ; [4..7]: VT bufs (4 + half*2 + dbuf)
  __shared__ bf16 smemAll[8][64 * 64];   // 64 KB
  __shared__ float bias_s[512];          // near window: k-q in [-255,255]
  const int tid = threadIdx.x;
  const int lane = tid & 63, w = tid >> 6;
  const int wl = w & 3, h2 = w >> 2;     // wave-in-group, KV half
  const int l15 = lane & 15, lhi = lane >> 4;
  const int wg = blockIdx.x;
  const int bh = wg & 31, qt = wg >> 5;
  const int b = bh >> 4, h = bh & 15;
  const int q0 = qt * 128;
  const int h1024 = h2 << 10;

  for (int i = tid; i < 511; i += 512)
    bias_s[i] = biasTab[h * NBIAS + 1792 + i];

  const float cL = rel_emb[15 * H_ + h] * LOG2E;
  const float cR = rel_emb[31 * H_ + h] * LOG2E;

  // Q fragments (scaled 0.125*log2e in QKV gemm): B-operand of swapped QK^T
  bf16x8 qa[2][2];
  {
    const bf16* Qbase = QKV + (size_t)(b * S_ + q0 + wl * 32) * LDQ + h * DK_;
#pragma unroll
    for (int qf = 0; qf < 2; ++qf)
#pragma unroll
      for (int c = 0; c < 2; ++c)
        qa[qf][c] = *(const bf16x8*)(Qbase + (size_t)(qf * 16 + l15) * LDQ + c * 32 + lhi * 8);
  }

  // hoisted LDS byte offsets (buf0 of own half; buf1 adds literal 8192)
  int koff[8];
#pragma unroll
  for (int kf = 0; kf < 4; ++kf)
#pragma unroll
    for (int c = 0; c < 2; ++c) {
      int krow = kf * 16 + l15;
      koff[kf * 2 + c] = ((krow * 64 + c * 32 + lhi * 8) ^ ((krow & 7) << 3)) * 2;
    }
  int voff[16];
#pragma unroll
  for (int df = 0; df < 4; ++df)
#pragma unroll
    for (int kf = 0; kf < 4; ++kf)
      voff[df * 4 + kf] =
          (((df * 16 + l15) * 64 + kf * 16 + lhi * 4) * 2) ^ ((l15 & 7) << 4);

  const char* kbase = (const char*)&smemAll[h2 * 2][0];
  const char* vbase = (const char*)&smemAll[4 + h2 * 2][0];

  float lpart[2] = {0.f, 0.f};
  f32x4 oacc[2][4] = {};

  const int urow = tid >> 3;                  // 0..63
  const int uswz = (tid & 7) ^ (urow & 7);
  const bf16* gk0 = QKV  + (size_t)(b * S_) * LDQ + 1024 + h * DK_
                         + (size_t)urow * LDQ + uswz * 8;
  const bf16* gk1 = gk0 + (size_t)1024 * LDQ;
  const bf16* gv0 = VTg_ + (size_t)(b * 1024 + h * DK_) * 2048
                         + (size_t)urow * 2048 + uswz * 8;
  const bf16* gv1 = gv0 + 1024;

  // ---- prologue: stage step 0 (both halves) into buf0
  async16(&smemAll[0][tid * 8], gk0);
  async16(&smemAll[2][tid * 8], gk1);
  async16(&smemAll[4][tid * 8], gv0);
  async16(&smemAll[6][tid * 8], gv1);
  gk0 += 64 * LDQ; gk1 += 64 * LDQ; gv0 += 64; gv1 += 64;
  __syncthreads();

#define TILE_BODY(CUR, KT, DO_PF)                                              \
  do {                                                                         \
    if (DO_PF) {                                                               \
      async16(&smemAll[0 + ((CUR) ^ 1)][tid * 8], gk0);                        \
      async16(&smemAll[2 + ((CUR) ^ 1)][tid * 8], gk1);                        \
      async16(&smemAll[4 + ((CUR) ^ 1)][tid * 8], gv0);                        \
      async16(&smemAll[6 + ((CUR) ^ 1)][tid * 8], gv1);                        \
      gk0 += 64 * LDQ; gk1 += 64 * LDQ; gv0 += 64; gv1 += 64;                  \
    }                                                                          \
    const int dk0 = h1024 + (KT) - q0;                                         \
    f32x4 st[2][4];                                                            \
    if (dk0 >= -128 && dk0 <= 192) {                                           \
      const int bb0 = dk0 + lhi * 4 - wl * 32 - l15 + 255;                     \
      _Pragma("unroll")                                                        \
      for (int qf = 0; qf < 2; ++qf)                                           \
        _Pragma("unroll")                                                      \
        for (int kf = 0; kf < 4; ++kf)                                         \
          _Pragma("unroll")                                                    \
          for (int r = 0; r < 4; ++r)                                          \
            st[qf][kf][r] = bias_s[bb0 + (kf - qf) * 16 + r];                  \
    } else {                                                                   \
      const float cq = (dk0 > 0) ? cR : cL;                                    \
      _Pragma("unroll")                                                        \
      for (int qf = 0; qf < 2; ++qf)                                           \
        _Pragma("unroll")                                                      \
        for (int kf = 0; kf < 4; ++kf)                                         \
          _Pragma("unroll")                                                    \
          for (int r = 0; r < 4; ++r)                                          \
            st[qf][kf][r] = cq;                                                \
    }                                                                          \
    _Pragma("unroll")                                                          \
    for (int kf = 0; kf < 4; ++kf) {                                           \
      _Pragma("unroll")                                                        \
      for (int c = 0; c < 2; ++c) {                                            \
        bf16x8 kb = *(const bf16x8*)(kbase + (CUR) * 8192 + koff[kf * 2 + c]); \
        st[0][kf] = mfma16(kb, qa[0][c], st[0][kf]);                           \
        st[1][kf] = mfma16(kb, qa[1][c], st[1][kf]);                           \
      }                                                                        \
    }                                                                          \
    bf16x4 pa[2][4];                                                           \
    _Pragma("unroll")                                                          \
    for (int qf = 0; qf < 2; ++qf) {                                           \
      float rs = 0.f;                                                          \
      _Pragma("unroll")                                                        \
      for (int kf = 0; kf < 4; ++kf)                                           \
        _Pragma("unroll")                                                      \
        for (int r = 0; r < 4; ++r) {                                          \
          float p = exp2_hw(st[qf][kf][r]);                                    \
          rs += p;                                                             \
          pa[qf][kf][r] = (bf16)p;                                             \
        }                                                                      \
      lpart[qf] += rs;                                                         \
    }                                                                          \
    _Pragma("unroll")                                                          \
    for (int df = 0; df < 4; ++df) {                                           \
      bf16x4 vb[4];                                                            \
      _Pragma("unroll")                                                        \
      for (int kf = 0; kf < 4; ++kf)                                           \
        vb[kf] = *(const bf16x4*)(vbase + (CUR) * 8192 + voff[df * 4 + kf]);   \
      _Pragma("unroll")                                                        \
      for (int qf = 0; qf < 2; ++qf)                                           \
        _Pragma("unroll")                                                      \
        for (int kf = 0; kf < 4; ++kf)                                         \
          oacc[qf][df] = mfma16k(pa[qf][kf], vb[kf], oacc[qf][df]);            \
    }                                                                          \
    __syncthreads();                                                           \
  } while (0)

  for (int tt = 0; tt < 8; ++tt) {
    const int ktbase = tt * 128;
    TILE_BODY(0, ktbase, true);
    TILE_BODY(1, ktbase + 64, tt < 7);
  }
#undef TILE_BODY

  // ---- merge halves: waves 4-7 publish partials, waves 0-3 accumulate.
  // Reuse retired K/V LDS (64KB >= 256 slots * 36 floats = 36.9KB).
  {
    float* M = (float*)&smemAll[0][0];
    const int slot = (wl * 64 + lane) * 36;
    if (h2 == 1) {
#pragma unroll
      for (int qf = 0; qf < 2; ++qf)
#pragma unroll
        for (int df = 0; df < 4; ++df)
          *(f32x4*)(M + slot + (qf * 4 + df) * 4) = oacc[qf][df];
      M[slot + 32] = lpart[0];
      M[slot + 33] = lpart[1];
    }
    __syncthreads();
    if (h2 == 0) {
#pragma unroll
      for (int qf = 0; qf < 2; ++qf)
#pragma unroll
        for (int df = 0; df < 4; ++df) {
          f32x4 o2 = *(const f32x4*)(M + slot + (qf * 4 + df) * 4);
#pragma unroll
          for (int r = 0; r < 4; ++r) oacc[qf][df][r] += o2[r];
        }
      lpart[0] += M[slot + 32];
      lpart[1] += M[slot + 33];

      // epilogue: reduce l across lane groups, normalize, store bf16
#pragma unroll
      for (int qf = 0; qf < 2; ++qf) {
        float lr0 = lpart[qf];
        lr0 += __shfl_xor(lr0, 16);
        lr0 += __shfl_xor(lr0, 32);
#pragma unroll
        for (int r = 0; r < 4; ++r) {
          float lr = __shfl(lr0, lhi * 4 + r);
          float inv = 1.0f / lr;
#pragma unroll
          for (int df = 0; df < 4; ++df) {
            int row = b * S_ + q0 + wl * 32 + qf * 16 + lhi * 4 + r;
            int col = h * DK_ + df * 16 + l15;
            Og[(size_t)row * D_ + col] = (bf16)(oacc[qf][df][r] * inv);
          }
        }
      }
    }
  }
}

// ---------------------------------------------------------------- launch
extern "C" void kernel_launch(void* const* d_in, const int* in_sizes, int n_in,
                              void* d_out, int out_size, void* d_ws, size_t ws_size,
                              hipStream_t stream) {
  const float* X   = (const float*)d_in[0];
  const float* Wq  = (const float*)d_in[1];
  const float* Wk  = (const float*)d_in[2];
  const float* Wv  = (const float*)d_in[3];
  const float* Wo  = (const float*)d_in[4];
  const float* rel = (const float*)d_in[5];
  float* out = (float*)d_out;
  char* ws = (char*)d_ws;
  const size_t MB = 1u << 20;
  bf16* Xb    = (bf16*)(ws + 0 * MB);    // 8 MB  (also reused as attn output Ob)
  bf16* Wqkvb = (bf16*)(ws + 8 * MB);    // 6 MB  [3072][1024]
  bf16* Wob   = (bf16*)(ws + 14 * MB);   // 2 MB
  bf16* QKVb  = (bf16*)(ws + 16 * MB);   // 24 MB [4096][3072] (V cols unused)
  bf16* VTb   = (bf16*)(ws + 40 * MB);   // 8 MB  [2048][2048]
  float* biasTab = (float*)(ws + 48 * MB);  // 16*4095*4 B

  // fused prep: X cvt + 4 weight cvts + bias table, one launch
  prep_kernel<<<8448, 256, 0, stream>>>(X, Wq, Wk, Wv, Wo, rel,
                                        Xb, Wqkvb, Wob, biasTab);

  // fused QKV projection; V cols written TRANSPOSED to VTb by epilogue
  gemm_bt<1, 4, 1><<<dim3(24, 32), 256, 0, stream>>>(Xb, Wqkvb, QKVb,
      VTb, /*vThr=*/2048,
      NROWS, 3 * D_, D_, /*colThr=*/1024, /*aQ=*/0.125f * LOG2E, /*a1=*/1.0f);

  attn_fwd<<<512, 512, 0, stream>>>(QKVb, VTb, biasTab, rel, Xb /*Ob*/);

  // out projection: 64x128 tiles -> 512 blocks
  gemm_bt<0, 2, 0><<<dim3(8, 64), 256, 0, stream>>>(Xb, Wob, out,
      nullptr, 1 << 30,
      NROWS, D_, D_, /*colThr=*/0, 1.0f, 1.0f);
}

// Round 13
// 116.364 us; speedup vs baseline: 1.2802x; 1.2802x over previous
//
#include <hip/hip_runtime.h>
#include <hip/hip_bf16.h>
#include <cstdint>
#include <cstddef>

typedef __bf16 bf16;
typedef __attribute__((ext_vector_type(8))) __bf16 bf16x8;
typedef __attribute__((ext_vector_type(4))) __bf16 bf16x4;
typedef __attribute__((ext_vector_type(4))) float f32x4;
typedef __attribute__((ext_vector_type(4))) short s16x4;

#define B_ 2
#define S_ 2048
#define D_ 1024
#define H_ 16
#define DK_ 64
#define NROWS (B_*S_)   // 4096
#define NBIAS 4095      // rel in [-2047,2047]
#define LDQ 3072        // fused QKV row stride
#define LOG2E 1.44269504f

__device__ __forceinline__ void async16(void* lds, const void* g) {
  __builtin_amdgcn_global_load_lds(
      (const __attribute__((address_space(1))) void*)g,
      (__attribute__((address_space(3))) void*)lds, 16, 0, 0);
}

__device__ __forceinline__ f32x4 mfma16(bf16x8 a, bf16x8 b, f32x4 c) {
  return __builtin_amdgcn_mfma_f32_16x16x32_bf16(a, b, c, 0, 0, 0);
}

__device__ __forceinline__ s16x4 bc4(bf16x4 x) {
  union { bf16x4 b; s16x4 s; } u; u.b = x; return u.s;
}

// K=16 MFMA: pairs with the swapped-QK^T C-layout (verified R3-R12).
__device__ __forceinline__ f32x4 mfma16k(bf16x4 a, bf16x4 b, f32x4 c) {
  return __builtin_amdgcn_mfma_f32_16x16x16bf16_1k(bc4(a), bc4(b), c, 0, 0, 0);
}

// Hazard-safe single-instruction HW exp2 (R8 lesson: raw asm corrupts).
__device__ __forceinline__ float exp2_hw(float x) {
  return __builtin_amdgcn_exp2f(x);
}

// -------------------------------------------------------- fused prep kernel
__global__ void prep_kernel(const float* __restrict__ X,
                            const float* __restrict__ Wq, const float* __restrict__ Wk,
                            const float* __restrict__ Wv, const float* __restrict__ Wo,
                            const float* __restrict__ rel_emb,
                            bf16* __restrict__ Xb, bf16* __restrict__ oqkv,
                            bf16* __restrict__ oo, float* __restrict__ tab) {
  const int bid = blockIdx.x;
  const int tid = threadIdx.x;
  if (bid < 4096) {
    int i = bid * 256 + tid;
    float4 v = ((const float4*)X)[i];
    bf16x4 o;
    o[0] = (bf16)v.x; o[1] = (bf16)v.y; o[2] = (bf16)v.z; o[3] = (bf16)v.w;
    ((bf16x4*)Xb)[i] = o;
  } else if (bid < 8192) {
    int widx = bid - 4096;
    int y = widx >> 10;
    const float* src = (y == 0) ? Wq : (y == 1) ? Wk : (y == 2) ? Wv : Wo;
    bf16* dst = (y < 3) ? (oqkv + (size_t)y * D_ * D_) : oo;
    int i = (widx & 1023) * 256 + tid;
    float4 v = ((const float4*)src)[i];
    bf16x4 o;
    o[0] = (bf16)v.x; o[1] = (bf16)v.y; o[2] = (bf16)v.z; o[3] = (bf16)v.w;
    ((bf16x4*)dst)[i] = o;
  } else {
    int idx = (bid - 8192) * 256 + tid;
    if (idx >= H_ * NBIAS) return;
    int h = idx / NBIAS;
    int p = idx - h * NBIAS;
    int rel = p - 2047;          // k - q  (mem - ctx)
    int n = -rel;                // per reference: n = -relative_position
    int ret = 0;
    if (n < 0) { ret = 16; n = -n; }
    int bucket;
    if (n < 8) {
      bucket = ret + n;
    } else {
      double v = log((double)n / 8.0) / log(16.0) * 8.0;
      int vi = 8 + (int)v;
      if (vi > 15) vi = 15;
      bucket = ret + vi;
    }
    tab[idx] = rel_emb[bucket * H_ + h] * LOG2E;
  }
}

// ---------------------------------------------------------------- GEMM (bt)
// C[M][N] = alpha * A[M][K] @ B[N][K]^T ; alpha = (n0 < colThr) ? a0 : a1
// Tile (MF*32) x 128 x BK64; 4 waves (2x2); wave (MF*16) x 64.
// VT_EP: blocks with n0 >= vThr write their tile TRANSPOSED to VT.
template<int OUT_BF16, int MF, int VT_EP>
__global__ __launch_bounds__(256, 3)
void gemm_bt(const bf16* __restrict__ A, const bf16* __restrict__ Bw,
             void* __restrict__ C, bf16* __restrict__ VT, int vThr,
             int M, int N, int K, int colThr, float a0, float a1) {
  __shared__ bf16 smem[MF * 32 * 64 + 128 * 64];
  bf16* As = smem;
  bf16* Bs = smem + MF * 32 * 64;
  const int tid = threadIdx.x;
  const int lane = tid & 63;
  const int w = tid >> 6;
  const int wr = w >> 1, wc = w & 1;
  const int l15 = lane & 15, lhi = lane >> 4;
  const int m0 = blockIdx.y * (MF * 32), n0 = blockIdx.x * 128;
  const float alpha = (n0 < colThr) ? a0 : a1;

  f32x4 acc[MF][4] = {};

  const int urow = tid >> 3;                 // 0..31
  const int uswz = (tid & 7) ^ (urow & 7);   // pre-swizzled global 16B unit
  const bf16* ga = A  + (size_t)(m0 + urow) * K + uswz * 8;
  const bf16* gb = Bw + (size_t)(n0 + urow) * K + uswz * 8;

  for (int kt = 0; kt < K; kt += 64) {
#pragma unroll
    for (int rnd = 0; rnd < MF; ++rnd)
      async16(As + tid * 8 + rnd * 2048, ga + kt + (size_t)(rnd * 32) * K);
#pragma unroll
    for (int rnd = 0; rnd < 4; ++rnd)
      async16(Bs + tid * 8 + rnd * 2048, gb + kt + (size_t)(rnd * 32) * K);
    __syncthreads();

#pragma unroll
    for (int kc = 0; kc < 2; ++kc) {
      bf16x8 af[MF], bfr[4];
#pragma unroll
      for (int m = 0; m < MF; ++m) {
        int row = wr * (MF * 16) + m * 16 + l15;
        int off = (row * 64 + kc * 32 + lhi * 8) ^ ((row & 7) << 3);
        af[m] = *(const bf16x8*)&As[off];
      }
#pragma unroll
      for (int n = 0; n < 4; ++n) {
        int row = wc * 64 + n * 16 + l15;
        int off = (row * 64 + kc * 32 + lhi * 8) ^ ((row & 7) << 3);
        bfr[n] = *(const bf16x8*)&Bs[off];
      }
      __builtin_amdgcn_s_setprio(1);
#pragma unroll
      for (int m = 0; m < MF; ++m)
#pragma unroll
        for (int n = 0; n < 4; ++n)
          acc[m][n] = mfma16(af[m], bfr[n], acc[m][n]);
      __builtin_amdgcn_s_setprio(0);
    }
    __syncthreads();
  }

  if (VT_EP && n0 >= vThr) {
    bf16* T = smem;  // 128*128 bf16 = 32 KB
#pragma unroll
    for (int m = 0; m < MF; ++m)
#pragma unroll
      for (int n = 0; n < 4; ++n)
#pragma unroll
        for (int r = 0; r < 4; ++r) {
          int rl = wr * (MF * 16) + m * 16 + lhi * 4 + r;  // s-local
          int cl = wc * 64 + n * 16 + l15;                 // d-local
          T[cl * 128 + (rl ^ ((cl & 7) << 3))] = (bf16)(acc[m][n][r] * alpha);
        }
    __syncthreads();
    const int bb = m0 >> 11, s0l = m0 & 2047, d0 = n0 - vThr;
    const int dr = tid >> 1, sh = tid & 1;
    bf16* dst = VT + ((size_t)(bb * 1024 + d0 + dr)) * 2048 + s0l + sh * 64;
    const bf16* src = T + dr * 128;
#pragma unroll
    for (int i = 0; i < 8; ++i) {
      int sb = sh * 8 + i;
      *(bf16x8*)(dst + i * 8) = *(const bf16x8*)(src + ((sb ^ (dr & 7)) * 8));
    }
    return;
  }

#pragma unroll
  for (int m = 0; m < MF; ++m)
#pragma unroll
    for (int n = 0; n < 4; ++n)
#pragma unroll
      for (int r = 0; r < 4; ++r) {
        int row = m0 + wr * (MF * 16) + m * 16 + lhi * 4 + r;
        int col = n0 + wc * 64 + n * 16 + l15;
        float v = acc[m][n][r] * alpha;
        if (OUT_BF16) ((bf16*)C)[(size_t)row * N + col] = (bf16)v;
        else          ((float*)C)[(size_t)row * N + col] = v;
      }
}

// ---------------------------------------------------------------- attention
// R13 = R12 structure with the register strangulation removed:
// __launch_bounds__(512, 2) instead of (512, 4).  R12's (512,4) capped
// VGPR at 64 (< ~88 live) -> scratch spills -> FETCH 67MB/WRITE 37MB and
// +60% duration.  With ~88 VGPR the HW still fits 2 blocks/CU (LDS-limited
// at 66KB) = 16 waves/CU = 4 waves/SIMD, now spill-free.
// 512 threads = 8 waves; waves 0-3 do KV [0,1024), waves 4-7 [1024,2048),
// same 128 q-rows; no-max softmax => halves merge by addition via LDS.
__global__ __launch_bounds__(512, 2)
void attn_fwd(const bf16* __restrict__ QKV, const bf16* __restrict__ VTg_,
              const float* __restrict__ biasTab, const float* __restrict__ rel_emb,
              bf16* __restrict__ Og) {
  // [0..3]: K bufs (half*2+dbuf) ; [4..7]: VT bufs (4 + half*2 + dbuf)
  __shared__ bf16 smemAll[8][64 * 64];   // 64 KB
  __shared__ float bias_s[512];          // near window: k-q in [-255,255]
  const int tid = threadIdx.x;
  const int lane = tid & 63, w = tid >> 6;
  const int wl = w & 3, h2 = w >> 2;     // wave-in-group, KV half
  const int l15 = lane & 15, lhi = lane >> 4;
  const int wg = blockIdx.x;
  const int bh = wg & 31, qt = wg >> 5;
  const int b = bh >> 4, h = bh & 15;
  const int q0 = qt * 128;
  const int h1024 = h2 << 10;

  for (int i = tid; i < 511; i += 512)
    bias_s[i] = biasTab[h * NBIAS + 1792 + i];

  const float cL = rel_emb[15 * H_ + h] * LOG2E;
  const float cR = rel_emb[31 * H_ + h] * LOG2E;

  // Q fragments (scaled 0.125*log2e in QKV gemm): B-operand of swapped QK^T
  bf16x8 qa[2][2];
  {
    const bf16* Qbase = QKV + (size_t)(b * S_ + q0 + wl * 32) * LDQ + h * DK_;
#pragma unroll
    for (int qf = 0; qf < 2; ++qf)
#pragma unroll
      for (int c = 0; c < 2; ++c)
        qa[qf][c] = *(const bf16x8*)(Qbase + (size_t)(qf * 16 + l15) * LDQ + c * 32 + lhi * 8);
  }

  // hoisted LDS byte offsets (buf0 of own half; buf1 adds literal 8192)
  int koff[8];
#pragma unroll
  for (int kf = 0; kf < 4; ++kf)
#pragma unroll
    for (int c = 0; c < 2; ++c) {
      int krow = kf * 16 + l15;
      koff[kf * 2 + c] = ((krow * 64 + c * 32 + lhi * 8) ^ ((krow & 7) << 3)) * 2;
    }
  int voff[16];
#pragma unroll
  for (int df = 0; df < 4; ++df)
#pragma unroll
    for (int kf = 0; kf < 4; ++kf)
      voff[df * 4 + kf] =
          (((df * 16 + l15) * 64 + kf * 16 + lhi * 4) * 2) ^ ((l15 & 7) << 4);

  const char* kbase = (const char*)&smemAll[h2 * 2][0];
  const char* vbase = (const char*)&smemAll[4 + h2 * 2][0];

  float lpart[2] = {0.f, 0.f};
  f32x4 oacc[2][4] = {};

  const int urow = tid >> 3;                  // 0..63
  const int uswz = (tid & 7) ^ (urow & 7);
  const bf16* gk0 = QKV  + (size_t)(b * S_) * LDQ + 1024 + h * DK_
                         + (size_t)urow * LDQ + uswz * 8;
  const bf16* gk1 = gk0 + (size_t)1024 * LDQ;
  const bf16* gv0 = VTg_ + (size_t)(b * 1024 + h * DK_) * 2048
                         + (size_t)urow * 2048 + uswz * 8;
  const bf16* gv1 = gv0 + 1024;

  // ---- prologue: stage step 0 (both halves) into buf0
  async16(&smemAll[0][tid * 8], gk0);
  async16(&smemAll[2][tid * 8], gk1);
  async16(&smemAll[4][tid * 8], gv0);
  async16(&smemAll[6][tid * 8], gv1);
  gk0 += 64 * LDQ; gk1 += 64 * LDQ; gv0 += 64; gv1 += 64;
  __syncthreads();

#define TILE_BODY(CUR, KT, DO_PF)                                              \
  do {                                                                         \
    if (DO_PF) {                                                               \
      async16(&smemAll[0 + ((CUR) ^ 1)][tid * 8], gk0);                        \
      async16(&smemAll[2 + ((CUR) ^ 1)][tid * 8], gk1);                        \
      async16(&smemAll[4 + ((CUR) ^ 1)][tid * 8], gv0);                        \
      async16(&smemAll[6 + ((CUR) ^ 1)][tid * 8], gv1);                        \
      gk0 += 64 * LDQ; gk1 += 64 * LDQ; gv0 += 64; gv1 += 64;                  \
    }                                                                          \
    const int dk0 = h1024 + (KT) - q0;                                         \
    f32x4 st[2][4];                                                            \
    if (dk0 >= -128 && dk0 <= 192) {                                           \
      const int bb0 = dk0 + lhi * 4 - wl * 32 - l15 + 255;                     \
      _Pragma("unroll")                                                        \
      for (int qf = 0; qf < 2; ++qf)                                           \
        _Pragma("unroll")                                                      \
        for (int kf = 0; kf < 4; ++kf)                                         \
          _Pragma("unroll")                                                    \
          for (int r = 0; r < 4; ++r)                                          \
            st[qf][kf][r] = bias_s[bb0 + (kf - qf) * 16 + r];                  \
    } else {                                                                   \
      const float cq = (dk0 > 0) ? cR : cL;                                    \
      _Pragma("unroll")                                                        \
      for (int qf = 0; qf < 2; ++qf)                                           \
        _Pragma("unroll")                                                      \
        for (int kf = 0; kf < 4; ++kf)                                         \
          _Pragma("unroll")                                                    \
          for (int r = 0; r < 4; ++r)                                          \
            st[qf][kf][r] = cq;                                                \
    }                                                                          \
    _Pragma("unroll")                                                          \
    for (int kf = 0; kf < 4; ++kf) {                                           \
      _Pragma("unroll")                                                        \
      for (int c = 0; c < 2; ++c) {                                            \
        bf16x8 kb = *(const bf16x8*)(kbase + (CUR) * 8192 + koff[kf * 2 + c]); \
        st[0][kf] = mfma16(kb, qa[0][c], st[0][kf]);                           \
        st[1][kf] = mfma16(kb, qa[1][c], st[1][kf]);                           \
      }                                                                        \
    }                                                                          \
    bf16x4 pa[2][4];                                                           \
    _Pragma("unroll")                                                          \
    for (int qf = 0; qf < 2; ++qf) {                                           \
      float rs = 0.f;                                                          \
      _Pragma("unroll")                                                        \
      for (int kf = 0; kf < 4; ++kf)                                           \
        _Pragma("unroll")                                                      \
        for (int r = 0; r < 4; ++r) {                                          \
          float p = exp2_hw(st[qf][kf][r]);                                    \
          rs += p;                                                             \
          pa[qf][kf][r] = (bf16)p;                                             \
        }                                                                      \
      lpart[qf] += rs;                                                         \
    }                                                                          \
    _Pragma("unroll")                                                          \
    for (int df = 0; df < 4; ++df) {                                           \
      bf16x4 vb[4];                                                            \
      _Pragma("unroll")                                                        \
      for (int kf = 0; kf < 4; ++kf)                                           \
        vb[kf] = *(const bf16x4*)(vbase + (CUR) * 8192 + voff[df * 4 + kf]);   \
      _Pragma("unroll")                                                        \
      for (int qf = 0; qf < 2; ++qf)                                           \
        _Pragma("unroll")                                                      \
        for (int kf = 0; kf < 4; ++kf)                                         \
          oacc[qf][df] = mfma16k(pa[qf][kf], vb[kf], oacc[qf][df]);            \
    }                                                                          \
    __syncthreads();                                                           \
  } while (0)

  for (int tt = 0; tt < 8; ++tt) {
    const int ktbase = tt * 128;
    TILE_BODY(0, ktbase, true);
    TILE_BODY(1, ktbase + 64, tt < 7);
  }
#undef TILE_BODY

  // ---- merge halves: waves 4-7 publish partials, waves 0-3 accumulate.
  // Reuse retired K/V LDS (64KB >= 256 slots * 36 floats = 36.9KB).
  {
    float* M = (float*)&smemAll[0][0];
    const int slot = (wl * 64 + lane) * 36;
    if (h2 == 1) {
#pragma unroll
      for (int qf = 0; qf < 2; ++qf)
#pragma unroll
        for (int df = 0; df < 4; ++df)
          *(f32x4*)(M + slot + (qf * 4 + df) * 4) = oacc[qf][df];
      M[slot + 32] = lpart[0];
      M[slot + 33] = lpart[1];
    }
    __syncthreads();
    if (h2 == 0) {
#pragma unroll
      for (int qf = 0; qf < 2; ++qf)
#pragma unroll
        for (int df = 0; df < 4; ++df) {
          f32x4 o2 = *(const f32x4*)(M + slot + (qf * 4 + df) * 4);
#pragma unroll
          for (int r = 0; r < 4; ++r) oacc[qf][df][r] += o2[r];
        }
      lpart[0] += M[slot + 32];
      lpart[1] += M[slot + 33];

      // epilogue: reduce l across lane groups, normalize, store bf16
#pragma unroll
      for (int qf = 0; qf < 2; ++qf) {
        float lr0 = lpart[qf];
        lr0 += __shfl_xor(lr0, 16);
        lr0 += __shfl_xor(lr0, 32);
#pragma unroll
        for (int r = 0; r < 4; ++r) {
          float lr = __shfl(lr0, lhi * 4 + r);
          float inv = 1.0f / lr;
#pragma unroll
          for (int df = 0; df < 4; ++df) {
            int row = b * S_ + q0 + wl * 32 + qf * 16 + lhi * 4 + r;
            int col = h * DK_ + df * 16 + l15;
            Og[(size_t)row * D_ + col] = (bf16)(oacc[qf][df][r] * inv);
          }
        }
      }
    }
  }
}

// ---------------------------------------------------------------- launch
extern "C" void kernel_launch(void* const* d_in, const int* in_sizes, int n_in,
                              void* d_out, int out_size, void* d_ws, size_t ws_size,
                              hipStream_t stream) {
  const float* X   = (const float*)d_in[0];
  const float* Wq  = (const float*)d_in[1];
  const float* Wk  = (const float*)d_in[2];
  const float* Wv  = (const float*)d_in[3];
  const float* Wo  = (const float*)d_in[4];
  const float* rel = (const float*)d_in[5];
  float* out = (float*)d_out;
  char* ws = (char*)d_ws;
  const size_t MB = 1u << 20;
  bf16* Xb    = (bf16*)(ws + 0 * MB);    // 8 MB  (also reused as attn output Ob)
  bf16* Wqkvb = (bf16*)(ws + 8 * MB);    // 6 MB  [3072][1024]
  bf16* Wob   = (bf16*)(ws + 14 * MB);   // 2 MB
  bf16* QKVb  = (bf16*)(ws + 16 * MB);   // 24 MB [4096][3072] (V cols unused)
  bf16* VTb   = (bf16*)(ws + 40 * MB);   // 8 MB  [2048][2048]
  float* biasTab = (float*)(ws + 48 * MB);  // 16*4095*4 B

  // fused prep: X cvt + 4 weight cvts + bias table, one launch
  prep_kernel<<<8448, 256, 0, stream>>>(X, Wq, Wk, Wv, Wo, rel,
                                        Xb, Wqkvb, Wob, biasTab);

  // fused QKV projection; V cols written TRANSPOSED to VTb by epilogue
  gemm_bt<1, 4, 1><<<dim3(24, 32), 256, 0, stream>>>(Xb, Wqkvb, QKVb,
      VTb, /*vThr=*/2048,
      NROWS, 3 * D_, D_, /*colThr=*/1024, /*aQ=*/0.125f * LOG2E, /*a1=*/1.0f);

  attn_fwd<<<512, 512, 0, stream>>>(QKVb, VTb, biasTab, rel, Xb /*Ob*/);

  // out projection: 64x128 tiles -> 512 blocks
  gemm_bt<0, 2, 0><<<dim3(8, 64), 256, 0, stream>>>(Xb, Wob, out,
      nullptr, 1 << 30,
      NROWS, D_, D_, /*colThr=*/0, 1.0f, 1.0f);
}

// Round 14
// 109.112 us; speedup vs baseline: 1.3653x; 1.0665x over previous
//
#include <hip/hip_runtime.h>
#include <hip/hip_bf16.h>
#include <cstdint>
#include <cstddef>

typedef __bf16 bf16;
typedef __attribute__((ext_vector_type(8))) __bf16 bf16x8;
typedef __attribute__((ext_vector_type(4))) __bf16 bf16x4;
typedef __attribute__((ext_vector_type(4))) float f32x4;
typedef __attribute__((ext_vector_type(4))) short s16x4;

#define B_ 2
#define S_ 2048
#define D_ 1024
#define H_ 16
#define DK_ 64
#define NROWS (B_*S_)   // 4096
#define NBIAS 4095      // rel in [-2047,2047]
#define LDQ 3072        // fused QKV row stride
#define LOG2E 1.44269504f

__device__ __forceinline__ void async16(void* lds, const void* g) {
  __builtin_amdgcn_global_load_lds(
      (const __attribute__((address_space(1))) void*)g,
      (__attribute__((address_space(3))) void*)lds, 16, 0, 0);
}

__device__ __forceinline__ f32x4 mfma16(bf16x8 a, bf16x8 b, f32x4 c) {
  return __builtin_amdgcn_mfma_f32_16x16x32_bf16(a, b, c, 0, 0, 0);
}

__device__ __forceinline__ s16x4 bc4(bf16x4 x) {
  union { bf16x4 b; s16x4 s; } u; u.b = x; return u.s;
}

// K=16 MFMA: pairs with the swapped-QK^T C-layout (verified R3-R13).
__device__ __forceinline__ f32x4 mfma16k(bf16x4 a, bf16x4 b, f32x4 c) {
  return __builtin_amdgcn_mfma_f32_16x16x16bf16_1k(bc4(a), bc4(b), c, 0, 0, 0);
}

// Hazard-safe single-instruction HW exp2 (R8 lesson: raw asm corrupts).
__device__ __forceinline__ float exp2_hw(float x) {
  return __builtin_amdgcn_exp2f(x);
}

// -------------------------------------------------------- fused prep kernel
__global__ void prep_kernel(const float* __restrict__ X,
                            const float* __restrict__ Wq, const float* __restrict__ Wk,
                            const float* __restrict__ Wv, const float* __restrict__ Wo,
                            const float* __restrict__ rel_emb,
                            bf16* __restrict__ Xb, bf16* __restrict__ oqkv,
                            bf16* __restrict__ oo, float* __restrict__ tab) {
  const int bid = blockIdx.x;
  const int tid = threadIdx.x;
  if (bid < 4096) {
    int i = bid * 256 + tid;
    float4 v = ((const float4*)X)[i];
    bf16x4 o;
    o[0] = (bf16)v.x; o[1] = (bf16)v.y; o[2] = (bf16)v.z; o[3] = (bf16)v.w;
    ((bf16x4*)Xb)[i] = o;
  } else if (bid < 8192) {
    int widx = bid - 4096;
    int y = widx >> 10;
    const float* src = (y == 0) ? Wq : (y == 1) ? Wk : (y == 2) ? Wv : Wo;
    bf16* dst = (y < 3) ? (oqkv + (size_t)y * D_ * D_) : oo;
    int i = (widx & 1023) * 256 + tid;
    float4 v = ((const float4*)src)[i];
    bf16x4 o;
    o[0] = (bf16)v.x; o[1] = (bf16)v.y; o[2] = (bf16)v.z; o[3] = (bf16)v.w;
    ((bf16x4*)dst)[i] = o;
  } else {
    int idx = (bid - 8192) * 256 + tid;
    if (idx >= H_ * NBIAS) return;
    int h = idx / NBIAS;
    int p = idx - h * NBIAS;
    int rel = p - 2047;          // k - q  (mem - ctx)
    int n = -rel;                // per reference: n = -relative_position
    int ret = 0;
    if (n < 0) { ret = 16; n = -n; }
    int bucket;
    if (n < 8) {
      bucket = ret + n;
    } else {
      double v = log((double)n / 8.0) / log(16.0) * 8.0;
      int vi = 8 + (int)v;
      if (vi > 15) vi = 15;
      bucket = ret + vi;
    }
    tab[idx] = rel_emb[bucket * H_ + h] * LOG2E;
  }
}

// ---------------------------------------------------------------- GEMM (bt)
// C[M][N] = alpha * A[M][K] @ B[N][K]^T ; alpha = (n0 < colThr) ? a0 : a1
// Tile (MF*32) x 128 x BK64; 4 waves (2x2); wave (MF*16) x 64.
// VT_EP: blocks with n0 >= vThr write their tile TRANSPOSED to VT.
template<int OUT_BF16, int MF, int VT_EP>
__global__ __launch_bounds__(256, 3)
void gemm_bt(const bf16* __restrict__ A, const bf16* __restrict__ Bw,
             void* __restrict__ C, bf16* __restrict__ VT, int vThr,
             int M, int N, int K, int colThr, float a0, float a1) {
  __shared__ bf16 smem[MF * 32 * 64 + 128 * 64];
  bf16* As = smem;
  bf16* Bs = smem + MF * 32 * 64;
  const int tid = threadIdx.x;
  const int lane = tid & 63;
  const int w = tid >> 6;
  const int wr = w >> 1, wc = w & 1;
  const int l15 = lane & 15, lhi = lane >> 4;
  const int m0 = blockIdx.y * (MF * 32), n0 = blockIdx.x * 128;
  const float alpha = (n0 < colThr) ? a0 : a1;

  f32x4 acc[MF][4] = {};

  const int urow = tid >> 3;                 // 0..31
  const int uswz = (tid & 7) ^ (urow & 7);   // pre-swizzled global 16B unit
  const bf16* ga = A  + (size_t)(m0 + urow) * K + uswz * 8;
  const bf16* gb = Bw + (size_t)(n0 + urow) * K + uswz * 8;

  for (int kt = 0; kt < K; kt += 64) {
#pragma unroll
    for (int rnd = 0; rnd < MF; ++rnd)
      async16(As + tid * 8 + rnd * 2048, ga + kt + (size_t)(rnd * 32) * K);
#pragma unroll
    for (int rnd = 0; rnd < 4; ++rnd)
      async16(Bs + tid * 8 + rnd * 2048, gb + kt + (size_t)(rnd * 32) * K);
    __syncthreads();

#pragma unroll
    for (int kc = 0; kc < 2; ++kc) {
      bf16x8 af[MF], bfr[4];
#pragma unroll
      for (int m = 0; m < MF; ++m) {
        int row = wr * (MF * 16) + m * 16 + l15;
        int off = (row * 64 + kc * 32 + lhi * 8) ^ ((row & 7) << 3);
        af[m] = *(const bf16x8*)&As[off];
      }
#pragma unroll
      for (int n = 0; n < 4; ++n) {
        int row = wc * 64 + n * 16 + l15;
        int off = (row * 64 + kc * 32 + lhi * 8) ^ ((row & 7) << 3);
        bfr[n] = *(const bf16x8*)&Bs[off];
      }
      __builtin_amdgcn_s_setprio(1);
#pragma unroll
      for (int m = 0; m < MF; ++m)
#pragma unroll
        for (int n = 0; n < 4; ++n)
          acc[m][n] = mfma16(af[m], bfr[n], acc[m][n]);
      __builtin_amdgcn_s_setprio(0);
    }
    __syncthreads();
  }

  if (VT_EP && n0 >= vThr) {
    bf16* T = smem;  // 128*128 bf16 = 32 KB
#pragma unroll
    for (int m = 0; m < MF; ++m)
#pragma unroll
      for (int n = 0; n < 4; ++n)
#pragma unroll
        for (int r = 0; r < 4; ++r) {
          int rl = wr * (MF * 16) + m * 16 + lhi * 4 + r;  // s-local
          int cl = wc * 64 + n * 16 + l15;                 // d-local
          T[cl * 128 + (rl ^ ((cl & 7) << 3))] = (bf16)(acc[m][n][r] * alpha);
        }
    __syncthreads();
    const int bb = m0 >> 11, s0l = m0 & 2047, d0 = n0 - vThr;
    const int dr = tid >> 1, sh = tid & 1;
    bf16* dst = VT + ((size_t)(bb * 1024 + d0 + dr)) * 2048 + s0l + sh * 64;
    const bf16* src = T + dr * 128;
#pragma unroll
    for (int i = 0; i < 8; ++i) {
      int sb = sh * 8 + i;
      *(bf16x8*)(dst + i * 8) = *(const bf16x8*)(src + ((sb ^ (dr & 7)) * 8));
    }
    return;
  }

#pragma unroll
  for (int m = 0; m < MF; ++m)
#pragma unroll
    for (int n = 0; n < 4; ++n)
#pragma unroll
      for (int r = 0; r < 4; ++r) {
        int row = m0 + wr * (MF * 16) + m * 16 + lhi * 4 + r;
        int col = n0 + wc * 64 + n * 16 + l15;
        float v = acc[m][n][r] * alpha;
        if (OUT_BF16) ((bf16*)C)[(size_t)row * N + col] = (bf16)v;
        else          ((float*)C)[(size_t)row * N + col] = v;
      }
}

// ---------------------------------------------------------------- attention
// R14 = R11 (QBLK=128, 256 thr, 4 waves, best attn structure) + ring-3
// K/V buffers with COUNTED vmcnt + raw s_barrier (T4): prefetch 2 steps
// ahead; per step wait vmcnt(4) (leaves next-next step's 4 loads in flight
// across the barrier) instead of __syncthreads()'s vmcnt(0) full drain.
// Loop unrolled 3x so all buffer offsets are compile-time literals.
__global__ __launch_bounds__(256, 2)
void attn_fwd(const bf16* __restrict__ QKV, const bf16* __restrict__ VTg_,
              const float* __restrict__ biasTab, const float* __restrict__ rel_emb,
              bf16* __restrict__ Og) {
  __shared__ bf16 Ks[3][64 * 64];    // ring of 3, [kpos][d] swizzled via source
  __shared__ bf16 VTs[3][64 * 64];   // ring of 3, [d][kpos] swizzled via source
  __shared__ float bias_s[512];      // near window: k-q in [-255,255]
  const int tid = threadIdx.x;
  const int lane = tid & 63, w = tid >> 6;
  const int l15 = lane & 15, lhi = lane >> 4;
  const int wg = blockIdx.x;
  const int bh = wg & 31, qt = wg >> 5;
  const int b = bh >> 4, h = bh & 15;
  const int q0 = qt * 128;

  // near-window bias: LDS i = (k-q)+255 ; global idx = (k-q)+2047 = i+1792
  for (int i = tid; i < 511; i += 256)
    bias_s[i] = biasTab[h * NBIAS + 1792 + i];

  // saturated-bucket constants: k-q <= -91 -> bucket15 ; k-q >= 91 -> bucket31
  const float cL = rel_emb[15 * H_ + h] * LOG2E;
  const float cR = rel_emb[31 * H_ + h] * LOG2E;

  // Q fragments (scaled 0.125*log2e in QKV gemm): B-operand of swapped QK^T
  bf16x8 qa[2][2];
  {
    const bf16* Qbase = QKV + (size_t)(b * S_ + q0 + w * 32) * LDQ + h * DK_;
#pragma unroll
    for (int qf = 0; qf < 2; ++qf)
#pragma unroll
      for (int c = 0; c < 2; ++c)
        qa[qf][c] = *(const bf16x8*)(Qbase + (size_t)(qf * 16 + l15) * LDQ + c * 32 + lhi * 8);
  }

  // hoisted LDS byte offsets (within one buffer; buffer base is a literal)
  int koff[8];
#pragma unroll
  for (int kf = 0; kf < 4; ++kf)
#pragma unroll
    for (int c = 0; c < 2; ++c) {
      int krow = kf * 16 + l15;
      koff[kf * 2 + c] = ((krow * 64 + c * 32 + lhi * 8) ^ ((krow & 7) << 3)) * 2;
    }
  int voff[16];
#pragma unroll
  for (int df = 0; df < 4; ++df)
#pragma unroll
    for (int kf = 0; kf < 4; ++kf)
      voff[df * 4 + kf] =
          (((df * 16 + l15) * 64 + kf * 16 + lhi * 4) * 2) ^ ((l15 & 7) << 4);

  float lpart[2] = {0.f, 0.f};
  f32x4 oacc[2][4] = {};

  const int urow = tid >> 3;                  // 0..31
  const int uswz = (tid & 7) ^ (urow & 7);    // 16B-unit swizzle (64-elem rows)
  const bf16* gk = QKV  + (size_t)(b * S_) * LDQ + 1024 + h * DK_
                        + (size_t)urow * LDQ + uswz * 8;
  const bf16* gv = VTg_ + (size_t)(b * 1024 + h * DK_) * 2048
                        + (size_t)urow * 2048 + uswz * 8;

  // ---- prologue: stage step 0 -> buf0, step 1 -> buf1 (issue order matters:
  // vmcnt is FIFO; the oldest 4 are step 0's).
  async16(&Ks[0][tid * 8],         gk);
  async16(&Ks[0][tid * 8 + 2048],  gk + 32 * LDQ);
  async16(&VTs[0][tid * 8],        gv);
  async16(&VTs[0][tid * 8 + 2048], gv + 32 * 2048);
  gk += 64 * LDQ;  gv += 64;
  async16(&Ks[1][tid * 8],         gk);
  async16(&Ks[1][tid * 8 + 2048],  gk + 32 * LDQ);
  async16(&VTs[1][tid * 8],        gv);
  async16(&VTs[1][tid * 8 + 2048], gv + 32 * 2048);
  gk += 64 * LDQ;  gv += 64;
  // step0 loads landed; lgkmcnt(0) publishes this wave's bias_s ds_writes
  // before the raw barrier (raw s_barrier has no implicit drain).
  asm volatile("s_waitcnt vmcnt(4) lgkmcnt(0)" ::: "memory");
  __builtin_amdgcn_s_barrier();

#define TILE_BODY(CUR, NXT, KT, DO_PF, WAITSTR)                                \
  do {                                                                         \
    if (DO_PF) {                                                               \
      async16(&Ks[NXT][tid * 8],         gk);                                  \
      async16(&Ks[NXT][tid * 8 + 2048],  gk + 32 * LDQ);                       \
      async16(&VTs[NXT][tid * 8],        gv);                                  \
      async16(&VTs[NXT][tid * 8 + 2048], gv + 32 * 2048);                      \
      gk += 64 * LDQ;  gv += 64;                                               \
    }                                                                          \
    const int dk0 = (KT) - q0;                                                 \
    f32x4 st[2][4];                                                            \
    if (dk0 >= -128 && dk0 <= 192) {                                           \
      const int bb0 = dk0 + lhi * 4 - w * 32 - l15 + 255;                      \
      _Pragma("unroll")                                                        \
      for (int qf = 0; qf < 2; ++qf)                                           \
        _Pragma("unroll")                                                      \
        for (int kf = 0; kf < 4; ++kf)                                         \
          _Pragma("unroll")                                                    \
          for (int r = 0; r < 4; ++r)                                          \
            st[qf][kf][r] = bias_s[bb0 + (kf - qf) * 16 + r];                  \
    } else {                                                                   \
      const float cq = (dk0 > 0) ? cR : cL;                                    \
      _Pragma("unroll")                                                        \
      for (int qf = 0; qf < 2; ++qf)                                           \
        _Pragma("unroll")                                                      \
        for (int kf = 0; kf < 4; ++kf)                                         \
          _Pragma("unroll")                                                    \
          for (int r = 0; r < 4; ++r)                                          \
            st[qf][kf][r] = cq;                                                \
    }                                                                          \
    _Pragma("unroll")                                                          \
    for (int kf = 0; kf < 4; ++kf) {                                           \
      _Pragma("unroll")                                                        \
      for (int c = 0; c < 2; ++c) {                                            \
        bf16x8 kb = *(const bf16x8*)((const char*)&Ks[CUR][0] +                \
                                     koff[kf * 2 + c]);                        \
        st[0][kf] = mfma16(kb, qa[0][c], st[0][kf]);                           \
        st[1][kf] = mfma16(kb, qa[1][c], st[1][kf]);                           \
      }                                                                        \
    }                                                                          \
    bf16x4 pa[2][4];                                                           \
    _Pragma("unroll")                                                          \
    for (int qf = 0; qf < 2; ++qf) {                                           \
      float rs = 0.f;                                                          \
      _Pragma("unroll")                                                        \
      for (int kf = 0; kf < 4; ++kf)                                           \
        _Pragma("unroll")                                                      \
        for (int r = 0; r < 4; ++r) {                                          \
          float p = exp2_hw(st[qf][kf][r]);                                    \
          rs += p;                                                             \
          pa[qf][kf][r] = (bf16)p;                                             \
        }                                                                      \
      lpart[qf] += rs;                                                         \
    }                                                                          \
    _Pragma("unroll")                                                          \
    for (int df = 0; df < 4; ++df) {                                           \
      bf16x4 vb[4];                                                            \
      _Pragma("unroll")                                                        \
      for (int kf = 0; kf < 4; ++kf)                                           \
        vb[kf] = *(const bf16x4*)((const char*)&VTs[CUR][0] +                  \
                                  voff[df * 4 + kf]);                          \
      _Pragma("unroll")                                                        \
      for (int qf = 0; qf < 2; ++qf)                                           \
        _Pragma("unroll")                                                      \
        for (int kf = 0; kf < 4; ++kf)                                         \
          oacc[qf][df] = mfma16k(pa[qf][kf], vb[kf], oacc[qf][df]);            \
    }                                                                          \
    asm volatile("s_waitcnt " WAITSTR ::: "memory");                           \
    __builtin_amdgcn_s_barrier();                                              \
  } while (0)

  // steady state: 8 loads in flight; wait 4 -> next step's buffer landed,
  // next-next step's 4 ride across the barrier (never vmcnt(0) mid-loop).
  for (int rr = 0; rr < 10; ++rr) {
    const int ktb = rr * 192;
    TILE_BODY(0, 2, ktb,       true,  "vmcnt(4)");
    TILE_BODY(1, 0, ktb + 64,  true,  "vmcnt(4)");
    TILE_BODY(2, 1, ktb + 128, true,  "vmcnt(4)");
  }
  TILE_BODY(0, 0, 1920, false, "vmcnt(0)");   // drains step-31's loads
  TILE_BODY(1, 0, 1984, false, "vmcnt(0)");
#undef TILE_BODY

  // epilogue: reduce l across lane groups, normalize, store bf16
#pragma unroll
  for (int qf = 0; qf < 2; ++qf) {
    float lr0 = lpart[qf];
    lr0 += __shfl_xor(lr0, 16);
    lr0 += __shfl_xor(lr0, 32);
#pragma unroll
    for (int r = 0; r < 4; ++r) {
      float lr = __shfl(lr0, lhi * 4 + r);
      float inv = 1.0f / lr;
#pragma unroll
      for (int df = 0; df < 4; ++df) {
        int row = b * S_ + q0 + w * 32 + qf * 16 + lhi * 4 + r;
        int col = h * DK_ + df * 16 + l15;
        Og[(size_t)row * D_ + col] = (bf16)(oacc[qf][df][r] * inv);
      }
    }
  }
}

// ---------------------------------------------------------------- launch
extern "C" void kernel_launch(void* const* d_in, const int* in_sizes, int n_in,
                              void* d_out, int out_size, void* d_ws, size_t ws_size,
                              hipStream_t stream) {
  const float* X   = (const float*)d_in[0];
  const float* Wq  = (const float*)d_in[1];
  const float* Wk  = (const float*)d_in[2];
  const float* Wv  = (const float*)d_in[3];
  const float* Wo  = (const float*)d_in[4];
  const float* rel = (const float*)d_in[5];
  float* out = (float*)d_out;
  char* ws = (char*)d_ws;
  const size_t MB = 1u << 20;
  bf16* Xb    = (bf16*)(ws + 0 * MB);    // 8 MB  (also reused as attn output Ob)
  bf16* Wqkvb = (bf16*)(ws + 8 * MB);    // 6 MB  [3072][1024]
  bf16* Wob   = (bf16*)(ws + 14 * MB);   // 2 MB
  bf16* QKVb  = (bf16*)(ws + 16 * MB);   // 24 MB [4096][3072] (V cols unused)
  bf16* VTb   = (bf16*)(ws + 40 * MB);   // 8 MB  [2048][2048]
  float* biasTab = (float*)(ws + 48 * MB);  // 16*4095*4 B

  // fused prep: X cvt + 4 weight cvts + bias table, one launch
  prep_kernel<<<8448, 256, 0, stream>>>(X, Wq, Wk, Wv, Wo, rel,
                                        Xb, Wqkvb, Wob, biasTab);

  // fused QKV projection; V cols written TRANSPOSED to VTb by epilogue
  gemm_bt<1, 4, 1><<<dim3(24, 32), 256, 0, stream>>>(Xb, Wqkvb, QKVb,
      VTb, /*vThr=*/2048,
      NROWS, 3 * D_, D_, /*colThr=*/1024, /*aQ=*/0.125f * LOG2E, /*a1=*/1.0f);

  attn_fwd<<<512, 256, 0, stream>>>(QKVb, VTb, biasTab, rel, Xb /*Ob*/);

  // out projection: 64x128 tiles -> 512 blocks
  gemm_bt<0, 2, 0><<<dim3(8, 64), 256, 0, stream>>>(Xb, Wob, out,
      nullptr, 1 << 30,
      NROWS, D_, D_, /*colThr=*/0, 1.0f, 1.0f);
}